// Round 17
// baseline (41.574 us; speedup 1.0000x reference)
//
#include <hip/hip_runtime.h>

#define NBINS 1024
#define IMG_HW 36864      // 192*192
#define T 256             // threads per block
#define BLKPI 144         // blocks per image (144*256 = IMG_HW)
#define NINST 32
#define CCH 16
#define NH 32
#define PADW 28672        // 256*256 - 192*192
#define NB 2
#define EPSF 1e-6f
#define NACC (NINST * (CCH + 1))   // 544

typedef unsigned long long u64;
typedef long long i64;
typedef float f32x4 __attribute__((ext_vector_type(4)));

// ------------------------------------------------------------------
// Workspace layout (bytes):
//   wg     : NB*NBINS*8   = 16384  (w in low32, gw in high32)
//   csum   : NB*544*8     =  8704  (global i64 fixed-point accumulators)
//   maxblk : NB*144*4     =  1152
//   meta   : 8*4          [scale0, scale1, -, -, G0, G1]
//   embT   : NB*IMG_HW*16*4 = 4.7MB (pixel-major emb copy, written by kA)
// ------------------------------------------------------------------
#define OFF_WG   0
#define OFF_CSUM 16384
#define OFF_MAXB 25088
#define OFF_META 26240
#define OFF_EMBT 65536

// k0: zero the global center accumulators (must precede kA's atomics).
// NOTE: no in-kernel device-scope sync anywhere — R13/R14 measured
// __threadfence + agent-scope ticket at +25-30us on 8 non-coherent XCDs.
__global__ void __launch_bounds__(256)
k_zero(u64* __restrict__ csum) {
    int tid = threadIdx.x;
    for (int i = tid; i < NB * NACC; i += 256) csum[i] = 0ull;
}

// kA: center sums in LDS (i64 fixed-point), flushed via global u64
// atomicAdd (integer => order-invariant => bit-deterministic). Also
// writes the pixel-major emb transpose (fire-and-forget coalesced stores)
// so kH loads 4x dwordx4 instead of 16 scattered dwords, plus per-block
// max|emb| and wg zeroing.
__global__ void __launch_bounds__(T)
k_centers(const float* __restrict__ emb, const int* __restrict__ gt,
          u64* __restrict__ csum, float* __restrict__ maxblk,
          u64* __restrict__ wg, f32x4* __restrict__ embT) {
    int blk = blockIdx.x, b = blockIdx.y;
    int tid = threadIdx.x;
    __shared__ i64 acc[NACC];
    __shared__ float mred[T / 64];

    // issue pixel loads first (overlap latency with LDS/wg zeroing)
    int pix = blk * T + tid;
    int gtv = gt[(size_t)b * IMG_HW + pix];
    const float* e = emb + (size_t)b * CCH * IMG_HW + pix;
    float ev[CCH];
    float me = 0.f;
#pragma unroll
    for (int c = 0; c < CCH; c++) {
        ev[c] = e[c * IMG_HW];
        me = fmaxf(me, fabsf(ev[c]));
    }

    for (int i = tid; i < NACC; i += T) acc[i] = 0;
    int gid = (b * BLKPI + blk) * T + tid;
    if (gid < NB * NBINS) wg[gid] = 0ull;
    __syncthreads();

    // pixel-major transpose store (64B contiguous per thread, coalesced)
    {
        f32x4* et = embT + (size_t)(b * IMG_HW + pix) * 4;
#pragma unroll
        for (int v = 0; v < 4; v++) {
            f32x4 t = {ev[v * 4 + 0], ev[v * 4 + 1], ev[v * 4 + 2], ev[v * 4 + 3]};
            et[v] = t;
        }
    }

    if (gtv > 0) {
        int n = gtv - 1;
#pragma unroll
        for (int c = 0; c < CCH; c++) {
            i64 fx = (i64)((double)ev[c] * 4294967296.0);
            atomicAdd((u64*)&acc[n * CCH + c], (u64)fx);
        }
        atomicAdd((u64*)&acc[NINST * CCH + n], 1ull);
    }
#pragma unroll
    for (int off = 32; off > 0; off >>= 1) me = fmaxf(me, __shfl_down(me, off, 64));
    if ((tid & 63) == 0) mred[tid >> 6] = me;
    __syncthreads();
    if (tid == 0) {
        float m = 0.f;
#pragma unroll
        for (int w = 0; w < T / 64; w++) m = fmaxf(m, mred[w]);
        maxblk[b * BLKPI + blk] = m;
    }
    u64* cb = csum + (size_t)b * NACC;
    for (int i = tid; i < NACC; i += T) {
        u64 v = (u64)acc[i];
        if (v) atomicAdd(&cb[i], v);
    }
}

// kHF: finalize-from-csum (8.7KB, L2-hot) + float4 MLP + LDS hist + flush.
__global__ void __launch_bounds__(T, 2)
k_hist(const f32x4* __restrict__ embT, const int* __restrict__ gt,
       const float* __restrict__ W1, const float* __restrict__ b1,
       const float* __restrict__ W2, const float* __restrict__ b2,
       const u64* __restrict__ csum, const float* __restrict__ maxblk,
       float* __restrict__ meta, u64* __restrict__ wg) {
    __shared__ unsigned int hist[NBINS];                 // 4 KB
    __shared__ __align__(16) float q_s[NINST][NH];       // 4 KB
    __shared__ float a_s[NINST][CCH];                    // 2 KB
    __shared__ float redf[T / 64], redm[T / 64];
    __shared__ float semax[NINST];
    __shared__ float scons[1];

    int pixblk = blockIdx.x, b = blockIdx.y;
    int tid = threadIdx.x;

    // issue pixel loads first (4x dwordx4 from the pixel-major copy)
    int pix = pixblk * T + tid;
    int gtv = gt[(size_t)b * IMG_HW + pix];
    const f32x4* et = embT + (size_t)(b * IMG_HW + pix) * 4;
    f32x4 u4[4];
#pragma unroll
    for (int v = 0; v < 4; v++) u4[v] = et[v];

    for (int i = tid; i < NBINS; i += T) hist[i] = 0u;

    // ---- finalize: a_s from csum (2 entries per thread) ----
    const u64* cb = csum + (size_t)b * NACC;
    float a_own = 0.f;
#pragma unroll
    for (int i = tid; i < NINST * CCH; i += T) {
        int n = i >> 4;
        float cnt = (float)(i64)cb[NINST * CCH + n] + EPSF;
        float a = (float)((double)(i64)cb[i] * (1.0 / 4294967296.0)) / cnt * (1.f / 32.f);
        a_s[n][i & 15] = a;
        a_own = fmaxf(a_own, fabsf(a));
    }
    float me = (tid < BLKPI) ? maxblk[b * BLKPI + tid] : 0.f;
#pragma unroll
    for (int off = 32; off > 0; off >>= 1) {
        me = fmaxf(me, __shfl_down(me, off, 64));
        a_own = fmaxf(a_own, __shfl_down(a_own, off, 64));
    }
    if ((tid & 63) == 0) { redf[tid >> 6] = me; redm[tid >> 6] = a_own; }
    __syncthreads();

    float maxug = 0.f, maxa = 0.f;
#pragma unroll
    for (int w = 0; w < T / 64; w++) {
        maxug = fmaxf(maxug, redf[w]);
        maxa = fmaxf(maxa, redm[w]);
    }
    maxug *= (1.f / 32.f);
    float b2v = b2[0];

    // ---- q + per-(n,j) interval bounds: 8 threads per n, 4 j's each ----
    {
        int n = tid >> 3, jg = tid & 7;
        float lo_sum = 0.f, hi_sum = 0.f;
#pragma unroll
        for (int jj = 0; jj < 4; jj++) {
            int j = jg * 4 + jj;
            float s = b1[j], smin = s, smax = s;
#pragma unroll
            for (int c = 0; c < CCH; c++) {
                float w = W1[c * NH + j];
                float av = a_s[n][c];
                float lo = fmaxf(av - maxug, -2.f);
                float hi = fminf(av + maxug, 2.f);
                s += av * w;
                if (w >= 0.f) { smin += lo * w; smax += hi * w; }
                else          { smin += hi * w; smax += lo * w; }
            }
            q_s[n][j] = s;
            float hlo = fmaxf(smin, 0.f), hhi = fmaxf(smax, 0.f);
            float w2 = W2[j];
            if (w2 >= 0.f) { lo_sum += hlo * w2; hi_sum += hhi * w2; }
            else           { lo_sum += hhi * w2; hi_sum += hlo * w2; }
        }
#pragma unroll
        for (int off = 4; off > 0; off >>= 1) {
            lo_sum += __shfl_down(lo_sum, off, 8);
            hi_sum += __shfl_down(hi_sum, off, 8);
        }
        if ((tid & 7) == 0)
            semax[n] = 1.f + fmaxf(b2v + hi_sum, -(b2v + lo_sum));
    }
    __syncthreads();
    if (tid < 32) {
        float mval = semax[tid];
#pragma unroll
        for (int off = 16; off > 0; off >>= 1) mval = fmaxf(mval, __shfl_down(mval, off, 32));
        if (tid == 0) {
            float sc = (float)NBINS / (mval + 1e-3f);
            scons[0] = sc;
            if (pixblk == 0) meta[b] = sc;
        }
    }
    if (pixblk == 0 && tid >= 64 && tid < 96) {
        float g = (float)(i64)cb[NINST * CCH + (tid - 64)];
#pragma unroll
        for (int off = 16; off > 0; off >>= 1) g += __shfl_down(g, off, 32);
        if (tid == 64) meta[4 + b] = g;
    }
    __syncthreads();
    float scale = scons[0];

    // ---- padded-region items (once per image): emb=0, label=0 ----
    if (pixblk == 0 && tid < NINST) {
        int n = tid;
        float logit = b2v;
        for (int j = 0; j < NH; j++) {
            float s = b1[j];
#pragma unroll
            for (int c = 0; c < CCH; c++)
                s += fminf(fmaxf(a_s[n][c], -2.f), 2.f) * W1[c * NH + j];
            logit += fmaxf(s, 0.f) * W2[j];
        }
        float er = 1.f + logit;
        if (er > 0.f) {
            int bin = min((int)(er * scale), NBINS - 1);
            atomicAdd(&wg[(size_t)b * NBINS + bin], (u64)PADW);
        }
    }

    // ---- MLP + LDS histogram ----
    float u[CCH];
    float maxu = 0.f;
#pragma unroll
    for (int c = 0; c < CCH; c++) {
        u[c] = u4[c >> 2][c & 3] * (1.f / 32.f);
        maxu = fmaxf(maxu, fabsf(u[c]));
    }

    if (maxu + maxa <= 2.f) {
        // no element can clip: h = relu(q_n - v), v shared across instances
        const f32x4 z4 = {0.f, 0.f, 0.f, 0.f};
        f32x4 v4[8];
#pragma unroll
        for (int jj = 0; jj < 8; jj++) v4[jj] = z4;
#pragma unroll
        for (int c = 0; c < CCH; c++) {
            const f32x4* w1r = reinterpret_cast<const f32x4*>(W1 + c * NH);
            float uc = u[c];
#pragma unroll
            for (int jj = 0; jj < 8; jj++) v4[jj] += uc * w1r[jj];
        }
        f32x4 w2v[8];
        {
            const f32x4* w2p = reinterpret_cast<const f32x4*>(W2);
#pragma unroll
            for (int jj = 0; jj < 8; jj++) w2v[jj] = w2p[jj];
        }
#pragma unroll 4
        for (int n = 0; n < NINST; n++) {
            const f32x4* qn = reinterpret_cast<const f32x4*>(&q_s[n][0]);
            f32x4 acc = z4;
#pragma unroll
            for (int jj = 0; jj < 8; jj++) {
                f32x4 t = qn[jj] - v4[jj];
                t[0] = fmaxf(t[0], 0.f);
                t[1] = fmaxf(t[1], 0.f);
                t[2] = fmaxf(t[2], 0.f);
                t[3] = fmaxf(t[3], 0.f);
                acc += t * w2v[jj];
            }
            float logit = b2v + ((acc[0] + acc[1]) + (acc[2] + acc[3]));
            unsigned int label = (gtv == n + 1) ? 1u : 0u;
            float er = label ? (1.f - logit) : (1.f + logit);
            if (er > 0.f) {
                int bin = min((int)(er * scale), NBINS - 1);
                atomicAdd(&hist[bin], 1u | (label << 16));
            }
        }
    } else {
        // exact slow path with per-element clip
        for (int n = 0; n < NINST; n++) {
            float logit = b2v;
            for (int j = 0; j < NH; j++) {
                float s = b1[j];
#pragma unroll
                for (int c = 0; c < CCH; c++) {
                    float f = fminf(fmaxf(a_s[n][c] - u[c], -2.f), 2.f);
                    s += f * W1[c * NH + j];
                }
                logit += fmaxf(s, 0.f) * W2[j];
            }
            unsigned int label = (gtv == n + 1) ? 1u : 0u;
            float er = label ? (1.f - logit) : (1.f + logit);
            if (er > 0.f) {
                int bin = min((int)(er * scale), NBINS - 1);
                atomicAdd(&hist[bin], 1u | (label << 16));
            }
        }
    }
    __syncthreads();
    {
        u64* wgb = wg + (size_t)b * NBINS;
        for (int i = tid; i < NBINS; i += T) {
            unsigned int h = hist[i];
            if (h) atomicAdd(&wgb[i], (u64)(h & 0xffffu) | ((u64)(h >> 16) << 32));
        }
    }
}

// kL: ONE 1024-thread block, both images sequentially; descending-bin
// Jaccard scan (1 bin/thread per image). Single writer -> plain store,
// no out zeroing, no atomics.
__global__ void __launch_bounds__(1024)
k_loss(const u64* __restrict__ wg, const float* __restrict__ meta,
       float* __restrict__ out) {
    int tid = threadIdx.x;
    __shared__ u64 wpart[16];
    __shared__ double dred[16];
    int lane = tid & 63, wid = tid >> 6;
    double total = 0.0;

    for (int b = 0; b < NB; b++) {
        const u64* wgb = wg + (size_t)b * NBINS;
        double G = (double)meta[4 + b];
        double invscale = 1.0 / (double)meta[b];

        int bin = NBINS - 1 - tid;
        u64 tot = wgb[bin];
        u64 incl = tot;
#pragma unroll
        for (int off = 1; off < 64; off <<= 1) {
            u64 x = __shfl_up(incl, off, 64);
            if (lane >= off) incl += x;
        }
        if (lane == 63) wpart[wid] = incl;
        __syncthreads();
        u64 woff = 0;
        for (int w = 0; w < wid; w++) woff += wpart[w];
        u64 excl = woff + incl - tot;
        unsigned int p = (unsigned int)(excl & 0xffffffffull);
        unsigned int cs = (unsigned int)(excl >> 32);

        double loss = 0.0;
        unsigned int w = (unsigned int)(tot & 0xffffffffull);
        unsigned int g = (unsigned int)(tot >> 32);
        if (G > 0.5 && w) {
            double Js = 1.0 - (G - (double)cs) / (G + (double)p - (double)cs);
            unsigned int pe = p + w, ce = cs + g;
            double Je = 1.0 - (G - (double)ce) / (G + (double)pe - (double)ce);
            double rep = ((double)bin + 0.5) * invscale;
            loss = rep * (Je - Js);
        }
#pragma unroll
        for (int off = 32; off > 0; off >>= 1) loss += __shfl_down(loss, off, 64);
        if (lane == 0) dred[wid] = loss;
        __syncthreads();
        if (tid == 0) {
            double t = 0;
            for (int ww = 0; ww < 16; ww++) t += dred[ww];
            total += t;
        }
        __syncthreads();   // before wpart/dred reuse for next image
    }
    if (tid == 0) out[0] = (float)(total * 0.5);  // mean over 2 images
}

extern "C" void kernel_launch(void* const* d_in, const int* in_sizes, int n_in,
                              void* d_out, int out_size, void* d_ws, size_t ws_size,
                              hipStream_t stream) {
    const float* emb = (const float*)d_in[0];
    const int* gt = (const int*)d_in[1];
    const float* W1 = (const float*)d_in[2];
    const float* b1 = (const float*)d_in[3];
    const float* W2 = (const float*)d_in[4];
    const float* b2 = (const float*)d_in[5];
    float* out = (float*)d_out;
    char* ws = (char*)d_ws;

    u64* wg = (u64*)(ws + OFF_WG);
    u64* csum = (u64*)(ws + OFF_CSUM);
    float* maxblk = (float*)(ws + OFF_MAXB);
    float* meta = (float*)(ws + OFF_META);
    f32x4* embT = (f32x4*)(ws + OFF_EMBT);

    k_zero<<<dim3(1), 256, 0, stream>>>(csum);
    k_centers<<<dim3(BLKPI, NB), T, 0, stream>>>(emb, gt, csum, maxblk, wg, embT);
    k_hist<<<dim3(BLKPI, NB), T, 0, stream>>>(embT, gt, W1, b1, W2, b2,
                                              csum, maxblk, meta, wg);
    k_loss<<<dim3(1), 1024, 0, stream>>>(wg, meta, out);
}

// Round 18
// 39.298 us; speedup vs baseline: 1.0579x; 1.0579x over previous
//
#include <hip/hip_runtime.h>

#define NBINS 1024
#define IMG_HW 36864      // 192*192
#define T 256             // threads per block
#define BLKPI 144         // blocks per image (144*256 = IMG_HW)
#define NINST 32
#define CCH 16
#define NH 32
#define PADW 28672        // 256*256 - 192*192
#define NB 2
#define EPSF 1e-6f
#define NACC (NINST * (CCH + 1))   // 544

typedef unsigned long long u64;
typedef long long i64;
typedef float f32x4 __attribute__((ext_vector_type(4)));

// ------------------------------------------------------------------
// Workspace layout (bytes):
//   wg     : NB*NBINS*8 = 16384  (w in low32, gw in high32)
//   csum   : NB*544*8   =  8704  (global i64 fixed-point accumulators)
//   maxblk : NB*144*4   =  1152
//   meta   : 8*4        [scale0, scale1, -, -, G0, G1]
// ------------------------------------------------------------------
#define OFF_WG   0
#define OFF_CSUM 16384
#define OFF_MAXB 25088
#define OFF_META 26240

// k0: zero the global center accumulators + out (precede kA's atomics).
// NOTE: no in-kernel device-scope sync anywhere — R13/R14 measured
// __threadfence + agent-scope ticket at +25-30us on 8 non-coherent XCDs;
// cooperative grid.sync was +130us (R5). Kernel boundaries only.
__global__ void __launch_bounds__(256)
k_zero(u64* __restrict__ csum, float* __restrict__ out) {
    int tid = threadIdx.x;
    for (int i = tid; i < NB * NACC; i += 256) csum[i] = 0ull;
    if (tid == 0) out[0] = 0.f;
}

// kA: center sums in LDS (i64 fixed-point), flushed via global u64
// atomicAdd (integer => order-invariant => bit-deterministic). Also
// per-block max|emb| and wg zeroing.
__global__ void __launch_bounds__(T)
k_centers(const float* __restrict__ emb, const int* __restrict__ gt,
          u64* __restrict__ csum, float* __restrict__ maxblk,
          u64* __restrict__ wg) {
    int blk = blockIdx.x, b = blockIdx.y;
    int tid = threadIdx.x;
    __shared__ i64 acc[NACC];
    __shared__ float mred[T / 64];

    // issue pixel loads first (overlap latency with LDS/wg zeroing)
    int pix = blk * T + tid;
    int gtv = gt[(size_t)b * IMG_HW + pix];
    const float* e = emb + (size_t)b * CCH * IMG_HW + pix;
    float ev[CCH];
    float me = 0.f;
#pragma unroll
    for (int c = 0; c < CCH; c++) {
        ev[c] = e[c * IMG_HW];
        me = fmaxf(me, fabsf(ev[c]));
    }

    for (int i = tid; i < NACC; i += T) acc[i] = 0;
    int gid = (b * BLKPI + blk) * T + tid;
    if (gid < NB * NBINS) wg[gid] = 0ull;
    __syncthreads();

    if (gtv > 0) {
        int n = gtv - 1;
#pragma unroll
        for (int c = 0; c < CCH; c++) {
            i64 fx = (i64)((double)ev[c] * 4294967296.0);
            atomicAdd((u64*)&acc[n * CCH + c], (u64)fx);
        }
        atomicAdd((u64*)&acc[NINST * CCH + n], 1ull);
    }
#pragma unroll
    for (int off = 32; off > 0; off >>= 1) me = fmaxf(me, __shfl_down(me, off, 64));
    if ((tid & 63) == 0) mred[tid >> 6] = me;
    __syncthreads();
    if (tid == 0) {
        float m = 0.f;
#pragma unroll
        for (int w = 0; w < T / 64; w++) m = fmaxf(m, mred[w]);
        maxblk[b * BLKPI + blk] = m;
    }
    u64* cb = csum + (size_t)b * NACC;
    for (int i = tid; i < NACC; i += T) {
        u64 v = (u64)acc[i];
        if (v) atomicAdd(&cb[i], v);
    }
}

// kHF: finalize-from-csum (8.7KB, L2-hot) + float4 MLP + LDS hist + flush.
__global__ void __launch_bounds__(T, 2)
k_hist(const float* __restrict__ emb, const int* __restrict__ gt,
       const float* __restrict__ W1, const float* __restrict__ b1,
       const float* __restrict__ W2, const float* __restrict__ b2,
       const u64* __restrict__ csum, const float* __restrict__ maxblk,
       float* __restrict__ meta, u64* __restrict__ wg) {
    __shared__ unsigned int hist[NBINS];                 // 4 KB
    __shared__ __align__(16) float q_s[NINST][NH];       // 4 KB
    __shared__ float a_s[NINST][CCH];                    // 2 KB
    __shared__ float redf[T / 64], redm[T / 64];
    __shared__ float semax[NINST];
    __shared__ float scons[1];

    int pixblk = blockIdx.x, b = blockIdx.y;
    int tid = threadIdx.x;

    // issue pixel loads first (overlap latency with the finalize phase)
    int pix = pixblk * T + tid;
    int gtv = gt[(size_t)b * IMG_HW + pix];
    const float* e = emb + (size_t)b * CCH * IMG_HW + pix;
    float u[CCH];
#pragma unroll
    for (int c = 0; c < CCH; c++) u[c] = e[c * IMG_HW];

    for (int i = tid; i < NBINS; i += T) hist[i] = 0u;

    // ---- finalize: a_s from csum (2 entries per thread) ----
    const u64* cb = csum + (size_t)b * NACC;
    float a_own = 0.f;
#pragma unroll
    for (int i = tid; i < NINST * CCH; i += T) {
        int n = i >> 4;
        float cnt = (float)(i64)cb[NINST * CCH + n] + EPSF;
        float a = (float)((double)(i64)cb[i] * (1.0 / 4294967296.0)) / cnt * (1.f / 32.f);
        a_s[n][i & 15] = a;
        a_own = fmaxf(a_own, fabsf(a));
    }
    float me = (tid < BLKPI) ? maxblk[b * BLKPI + tid] : 0.f;
#pragma unroll
    for (int off = 32; off > 0; off >>= 1) {
        me = fmaxf(me, __shfl_down(me, off, 64));
        a_own = fmaxf(a_own, __shfl_down(a_own, off, 64));
    }
    if ((tid & 63) == 0) { redf[tid >> 6] = me; redm[tid >> 6] = a_own; }
    __syncthreads();

    float maxug = 0.f, maxa = 0.f;
#pragma unroll
    for (int w = 0; w < T / 64; w++) {
        maxug = fmaxf(maxug, redf[w]);
        maxa = fmaxf(maxa, redm[w]);
    }
    maxug *= (1.f / 32.f);
    float b2v = b2[0];

    // ---- q + per-(n,j) interval bounds: 8 threads per n, 4 j's each ----
    {
        int n = tid >> 3, jg = tid & 7;
        float lo_sum = 0.f, hi_sum = 0.f;
#pragma unroll
        for (int jj = 0; jj < 4; jj++) {
            int j = jg * 4 + jj;
            float s = b1[j], smin = s, smax = s;
#pragma unroll
            for (int c = 0; c < CCH; c++) {
                float w = W1[c * NH + j];
                float av = a_s[n][c];
                float lo = fmaxf(av - maxug, -2.f);
                float hi = fminf(av + maxug, 2.f);
                s += av * w;
                if (w >= 0.f) { smin += lo * w; smax += hi * w; }
                else          { smin += hi * w; smax += lo * w; }
            }
            q_s[n][j] = s;
            float hlo = fmaxf(smin, 0.f), hhi = fmaxf(smax, 0.f);
            float w2 = W2[j];
            if (w2 >= 0.f) { lo_sum += hlo * w2; hi_sum += hhi * w2; }
            else           { lo_sum += hhi * w2; hi_sum += hlo * w2; }
        }
#pragma unroll
        for (int off = 4; off > 0; off >>= 1) {
            lo_sum += __shfl_down(lo_sum, off, 8);
            hi_sum += __shfl_down(hi_sum, off, 8);
        }
        if ((tid & 7) == 0)
            semax[n] = 1.f + fmaxf(b2v + hi_sum, -(b2v + lo_sum));
    }
    __syncthreads();
    if (tid < 32) {
        float mval = semax[tid];
#pragma unroll
        for (int off = 16; off > 0; off >>= 1) mval = fmaxf(mval, __shfl_down(mval, off, 32));
        if (tid == 0) {
            float sc = (float)NBINS / (mval + 1e-3f);
            scons[0] = sc;
            if (pixblk == 0) meta[b] = sc;
        }
    }
    if (pixblk == 0 && tid >= 64 && tid < 96) {
        float g = (float)(i64)cb[NINST * CCH + (tid - 64)];
#pragma unroll
        for (int off = 16; off > 0; off >>= 1) g += __shfl_down(g, off, 32);
        if (tid == 64) meta[4 + b] = g;
    }
    __syncthreads();
    float scale = scons[0];

    // ---- padded-region items (once per image): emb=0, label=0 ----
    if (pixblk == 0 && tid < NINST) {
        int n = tid;
        float logit = b2v;
        for (int j = 0; j < NH; j++) {
            float s = b1[j];
#pragma unroll
            for (int c = 0; c < CCH; c++)
                s += fminf(fmaxf(a_s[n][c], -2.f), 2.f) * W1[c * NH + j];
            logit += fmaxf(s, 0.f) * W2[j];
        }
        float er = 1.f + logit;
        if (er > 0.f) {
            int bin = min((int)(er * scale), NBINS - 1);
            atomicAdd(&wg[(size_t)b * NBINS + bin], (u64)PADW);
        }
    }

    // ---- MLP + LDS histogram ----
    float maxu = 0.f;
#pragma unroll
    for (int c = 0; c < CCH; c++) {
        u[c] *= (1.f / 32.f);
        maxu = fmaxf(maxu, fabsf(u[c]));
    }

    if (maxu + maxa <= 2.f) {
        // no element can clip: h = relu(q_n - v), v shared across instances
        const f32x4 z4 = {0.f, 0.f, 0.f, 0.f};
        f32x4 v4[8];
#pragma unroll
        for (int jj = 0; jj < 8; jj++) v4[jj] = z4;
#pragma unroll
        for (int c = 0; c < CCH; c++) {
            const f32x4* w1r = reinterpret_cast<const f32x4*>(W1 + c * NH);
            float uc = u[c];
#pragma unroll
            for (int jj = 0; jj < 8; jj++) v4[jj] += uc * w1r[jj];
        }
        f32x4 w2v[8];
        {
            const f32x4* w2p = reinterpret_cast<const f32x4*>(W2);
#pragma unroll
            for (int jj = 0; jj < 8; jj++) w2v[jj] = w2p[jj];
        }
#pragma unroll 4
        for (int n = 0; n < NINST; n++) {
            const f32x4* qn = reinterpret_cast<const f32x4*>(&q_s[n][0]);
            f32x4 acc = z4;
#pragma unroll
            for (int jj = 0; jj < 8; jj++) {
                f32x4 t = qn[jj] - v4[jj];
                t[0] = fmaxf(t[0], 0.f);
                t[1] = fmaxf(t[1], 0.f);
                t[2] = fmaxf(t[2], 0.f);
                t[3] = fmaxf(t[3], 0.f);
                acc += t * w2v[jj];
            }
            float logit = b2v + ((acc[0] + acc[1]) + (acc[2] + acc[3]));
            unsigned int label = (gtv == n + 1) ? 1u : 0u;
            float er = label ? (1.f - logit) : (1.f + logit);
            if (er > 0.f) {
                int bin = min((int)(er * scale), NBINS - 1);
                atomicAdd(&hist[bin], 1u | (label << 16));
            }
        }
    } else {
        // exact slow path with per-element clip
        for (int n = 0; n < NINST; n++) {
            float logit = b2v;
            for (int j = 0; j < NH; j++) {
                float s = b1[j];
#pragma unroll
                for (int c = 0; c < CCH; c++) {
                    float f = fminf(fmaxf(a_s[n][c] - u[c], -2.f), 2.f);
                    s += f * W1[c * NH + j];
                }
                logit += fmaxf(s, 0.f) * W2[j];
            }
            unsigned int label = (gtv == n + 1) ? 1u : 0u;
            float er = label ? (1.f - logit) : (1.f + logit);
            if (er > 0.f) {
                int bin = min((int)(er * scale), NBINS - 1);
                atomicAdd(&hist[bin], 1u | (label << 16));
            }
        }
    }
    __syncthreads();
    {
        u64* wgb = wg + (size_t)b * NBINS;
        for (int i = tid; i < NBINS; i += T) {
            unsigned int h = hist[i];
            if (h) atomicAdd(&wgb[i], (u64)(h & 0xffffu) | ((u64)(h >> 16) << 32));
        }
    }
}

// kL: one 1024-thread block per image; descending-bin Jaccard scan
// (1 bin/thread). out += 0.5*loss per image (2 commutative float adds).
__global__ void __launch_bounds__(1024)
k_loss(const u64* __restrict__ wg, const float* __restrict__ meta,
       float* __restrict__ out) {
    int b = blockIdx.x;
    int tid = threadIdx.x;
    const u64* wgb = wg + (size_t)b * NBINS;
    double G = (double)meta[4 + b];
    double invscale = 1.0 / (double)meta[b];

    int bin = NBINS - 1 - tid;
    u64 tot = wgb[bin];
    u64 incl = tot;
    int lane = tid & 63, wid = tid >> 6;
#pragma unroll
    for (int off = 1; off < 64; off <<= 1) {
        u64 x = __shfl_up(incl, off, 64);
        if (lane >= off) incl += x;
    }
    __shared__ u64 wpart[16];
    __shared__ double dred[16];
    if (lane == 63) wpart[wid] = incl;
    __syncthreads();
    u64 woff = 0;
    for (int w = 0; w < wid; w++) woff += wpart[w];
    u64 excl = woff + incl - tot;
    unsigned int p = (unsigned int)(excl & 0xffffffffull);
    unsigned int cs = (unsigned int)(excl >> 32);

    double loss = 0.0;
    unsigned int w = (unsigned int)(tot & 0xffffffffull);
    unsigned int g = (unsigned int)(tot >> 32);
    if (G > 0.5 && w) {
        double Js = 1.0 - (G - (double)cs) / (G + (double)p - (double)cs);
        unsigned int pe = p + w, ce = cs + g;
        double Je = 1.0 - (G - (double)ce) / (G + (double)pe - (double)ce);
        double rep = ((double)bin + 0.5) * invscale;
        loss = rep * (Je - Js);
    }
#pragma unroll
    for (int off = 32; off > 0; off >>= 1) loss += __shfl_down(loss, off, 64);
    if (lane == 0) dred[wid] = loss;
    __syncthreads();
    if (tid == 0) {
        double t = 0;
        for (int ww = 0; ww < 16; ww++) t += dred[ww];
        atomicAdd(out, (float)(t * 0.5));  // mean over 2 images
    }
}

extern "C" void kernel_launch(void* const* d_in, const int* in_sizes, int n_in,
                              void* d_out, int out_size, void* d_ws, size_t ws_size,
                              hipStream_t stream) {
    const float* emb = (const float*)d_in[0];
    const int* gt = (const int*)d_in[1];
    const float* W1 = (const float*)d_in[2];
    const float* b1 = (const float*)d_in[3];
    const float* W2 = (const float*)d_in[4];
    const float* b2 = (const float*)d_in[5];
    float* out = (float*)d_out;
    char* ws = (char*)d_ws;

    u64* wg = (u64*)(ws + OFF_WG);
    u64* csum = (u64*)(ws + OFF_CSUM);
    float* maxblk = (float*)(ws + OFF_MAXB);
    float* meta = (float*)(ws + OFF_META);

    k_zero<<<dim3(1), 256, 0, stream>>>(csum, out);
    k_centers<<<dim3(BLKPI, NB), T, 0, stream>>>(emb, gt, csum, maxblk, wg);
    k_hist<<<dim3(BLKPI, NB), T, 0, stream>>>(emb, gt, W1, b1, W2, b2,
                                              csum, maxblk, meta, wg);
    k_loss<<<dim3(NB), 1024, 0, stream>>>(wg, meta, out);
}